// Round 2
// baseline (207.746 us; speedup 1.0000x reference)
//
#include <hip/hip_runtime.h>

// Camera back-projection, R2: gather-coalesced layout + LDS transpose.
//
// out[n,0,ix,iy,iz] = 1 - 128 * tdf ;  tdf = min(|zc-d|, 1/128) or 1/128.
// u depends on (ix,iz), v depends on (iy,iz). Lanes vary along ix so each
// wave's depth gather reads one image-row segment (~6-9 cache lines instead
// of ~64 when lanes varied along iz -> R1's 175us txn-split bottleneck).
// Stores are iz-contiguous, so each 16-iz chunk is transposed through LDS:
// compute into tile[ix][iz], then store with lanes walking iz (16 fully
// covered 64B lines per wave store = optimal).
//
// Numerics: exact IEEE '/' and rintf (half-to-even) -> bit-exact vs numpy
// (R1 absmax was 0.0). Per-iz v = fy/zc is block-uniform: precomputed once
// per block into LDS (halves division count; bitwise identical).

#define RES 128
#define IMG 480
#define CHUNK 16
#define LROW 20   // LDS tile row stride in floats (16B-aligned, depolarizes banks)

__global__ __launch_bounds__(128) void cbp_kernel(
    const float* __restrict__ depth,
    const float* __restrict__ fl,
    const float* __restrict__ cam_dist,
    float* __restrict__ out)
{
    __shared__ float s_tile[RES * LROW];   // 128 ix rows x 16 iz (padded) = 10 KB
    __shared__ float s_zc[RES];
    __shared__ int   s_vrow[RES];          // vi * IMG
    __shared__ int   s_vok[RES];           // v in [0,479] && zc > 0

    const int iy = blockIdx.x & (RES - 1);
    const int n  = blockIdx.x >> 7;
    const int t  = threadIdx.x;            // 0..127 -> ix in compute phase

    const float flv = fl[n];
    const float cd  = cam_dist[n];
    const float trunc = 1.0f / 128.0f;

    // ---- per-iz precompute (block-uniform quantities), one iz per thread ----
    {
        const int iz = t;
        const float y  = (iy + 0.5f) / 128.0f - 0.5f;
        const float fy = flv * y;
        const float z  = (iz + 0.5f) / 128.0f - 0.5f;
        const float zc = cd - z;
        const float v  = fy / zc + (float)(IMG - 1) * 0.5f;   // IEEE div, matches ref
        const float vr = rintf(v);                            // half-to-even
        const int   vi = (int)fminf(fmaxf(vr, 0.0f), (float)(IMG - 1));
        s_zc[iz]   = zc;
        s_vrow[iz] = vi * IMG;
        s_vok[iz]  = (v >= 0.0f) && (v <= (float)(IMG - 1)) && (zc > 0.0f);
    }
    __syncthreads();

    const int   ix = t;
    const float x  = (ix + 0.5f) / 128.0f - 0.5f;
    const float fx = flv * x;
    const float* __restrict__ dimg = depth + (size_t)n * (IMG * IMG);

    // output base for this (n, iy), in floats
    const size_t obase = (size_t)n * (RES * RES * RES) + (size_t)iy * RES;

    for (int c = 0; c < RES / CHUNK; ++c) {
        const int iz0 = c * CHUNK;

        // ---- compute phase: lanes = ix, gather along image rows ----
#pragma unroll
        for (int j = 0; j < CHUNK; ++j) {
            const int   iz = iz0 + j;
            const float zc = s_zc[iz];
            const float u  = fx / zc + (float)(IMG - 1) * 0.5f;  // IEEE div
            const float ur = rintf(u);
            const int   ui = (int)fminf(fmaxf(ur, 0.0f), (float)(IMG - 1));
            const float d  = dimg[s_vrow[iz] + ui];
            const bool ok  = s_vok[iz] && (u >= 0.0f) && (u <= (float)(IMG - 1))
                             && (d > 0.0f);
            float tdf = fminf(fabsf(zc - d), trunc);
            tdf = ok ? tdf : trunc;
            s_tile[ix * LROW + j] = 1.0f - 128.0f * tdf;
        }
        __syncthreads();

        // ---- store phase: lanes walk iz -> fully coalesced float4 stores ----
#pragma unroll
        for (int r = 0; r < 4; ++r) {
            const int f   = r * 128 + t;     // 512 float4s in tile
            const int ixf = f >> 2;
            const int q   = f & 3;
            const float4 val = *(const float4*)&s_tile[ixf * LROW + q * 4];
            float4* dst = (float4*)&out[obase + (size_t)ixf * (RES * RES) + iz0 + q * 4];
            *dst = val;
        }
        __syncthreads();
    }
}

extern "C" void kernel_launch(void* const* d_in, const int* in_sizes, int n_in,
                              void* d_out, int out_size, void* d_ws, size_t ws_size,
                              hipStream_t stream) {
    const float* depth = (const float*)d_in[0];
    const float* fl    = (const float*)d_in[1];
    const float* cd    = (const float*)d_in[2];
    float* out         = (float*)d_out;

    const int N = in_sizes[1];             // fl is (N,1)
    const int grid = N * RES;              // one block per (n, iy)
    cbp_kernel<<<grid, 128, 0, stream>>>(depth, fl, cd, out);
}